// Round 12
// baseline (169.353 us; speedup 1.0000x reference)
//
#include <hip/hip_runtime.h>
#include <hip/hip_bf16.h>
#include <hip/hip_fp16.h>

#define B_ 64
#define V_ 64
#define E_ 4032
#define HID_ 128
#define IN_ 32
#define BV_ (B_ * V_)

typedef __attribute__((ext_vector_type(8))) _Float16 f16x8;
typedef __attribute__((ext_vector_type(4))) float f32x4;

// ---------------- Kernel 1: merged prep ----------------
// seg0 [0,1024):     h1 halves (f16), 4 nodes/block
// seg1 [1024,1216):  W2 -> f16 fragment order (2x2-split layout)
// seg2 [1216,1376):  fc1/fc2/mu -> f16 fragment order (out kernel layout)
// seg3 [1376,1504):  x -> f16
// seg4 [1504,1568):  edges -> ewT via LDS staging (1 b per block)
__global__ void __launch_bounds__(256) prep_all(
    const float* __restrict__ x, const float* __restrict__ w1,
    const float* __restrict__ b1, const float* __restrict__ w2,
    const float* __restrict__ edges, const float* __restrict__ fc1w,
    const float* __restrict__ fc2w, const float* __restrict__ muw,
    _Float16* __restrict__ h1r, _Float16* __restrict__ h1s,
    _Float16* __restrict__ w2f, _Float16* __restrict__ fc1f,
    _Float16* __restrict__ fc2f, _Float16* __restrict__ muf,
    _Float16* __restrict__ xh, float* __restrict__ ewT) {
  const int bid = blockIdx.x, t = threadIdx.x;

  if (bid < 1024) {  // ---- h1 halves, 4 nodes/block ----
    __shared__ float xs[4][IN_];
    if (t < 128) xs[t >> 5][t & 31] = x[bid * 128 + t];
    __syncthreads();
    const int h = t & 127, half_ = t >> 7;
#pragma unroll
    for (int tt = 0; tt < 3; ++tt) {
      const float* wrow = w1 + ((size_t)((tt + 1) * HID_ + h)) * (2 * IN_) + half_ * IN_;
      float4 w[8];
#pragma unroll
      for (int j = 0; j < 8; ++j) w[j] = ((const float4*)wrow)[j];
      const float bias = half_ ? 0.f : b1[(tt + 1) * HID_ + h];
      _Float16* dst = (half_ ? h1s : h1r) + ((size_t)tt * BV_ + bid * 4) * HID_ + h;
#pragma unroll
      for (int n = 0; n < 4; ++n) {
        float acc = bias;
#pragma unroll
        for (int j = 0; j < 8; ++j)
          acc += w[j].x * xs[n][4 * j] + w[j].y * xs[n][4 * j + 1] +
                 w[j].z * xs[n][4 * j + 2] + w[j].w * xs[n][4 * j + 3];
        dst[n * HID_] = (_Float16)acc;
      }
    }
    return;
  }
  if (bid < 1216) {  // ---- W2 fragment order: ((((tt*2+nh2)*4+nt4)*4+ks)*64+lane)*8+e
    const int i = (bid - 1024) * 256 + t;
    const int e = i & 7, lane = (i >> 3) & 63, ks = (i >> 9) & 3;
    const int nt4 = (i >> 11) & 3, nh2 = (i >> 13) & 1, tt = i >> 14;
    const int o = nh2 * 64 + nt4 * 16 + (lane & 15);
    const int k = ks * 32 + (lane >> 4) * 8 + e;
    w2f[i] = (_Float16)w2[((size_t)((tt + 1) * HID_ + o)) * HID_ + k];
    return;
  }
  if (bid < 1376) {  // ---- out-MLP weights, fragment order ----
    int i = (bid - 1216) * 256 + t;
    if (i < 20480) {  // fc1f: ((ntg*5+ks)*64+lane)*8+e
      const int e = i & 7, lane = (i >> 3) & 63, rest = i >> 9;
      const int ks = rest % 5, ntg = rest / 5;
      const int o = ntg * 16 + (lane & 15);
      const int k = ks * 32 + (lane >> 4) * 8 + e;
      fc1f[i] = (_Float16)fc1w[(size_t)o * (IN_ + HID_) + k];
      return;
    }
    i -= 20480;
    if (i < 16384) {  // fc2f
      const int e = i & 7, lane = (i >> 3) & 63, rest = i >> 9;
      const int ks = rest & 3, ntg = rest >> 2;
      const int o = ntg * 16 + (lane & 15);
      const int k = ks * 32 + (lane >> 4) * 8 + e;
      fc2f[i] = (_Float16)fc2w[(size_t)o * HID_ + k];
      return;
    }
    i -= 16384;
    {  // muf
      const int e = i & 7, lane = (i >> 3) & 63, rest = i >> 9;
      const int ks = rest & 3, ntg = rest >> 2;
      const int o = ntg * 16 + (lane & 15);
      const int k = ks * 32 + (lane >> 4) * 8 + e;
      muf[i] = (_Float16)muw[(size_t)o * HID_ + k];
      return;
    }
  }
  if (bid < 1504) {  // ---- x -> f16 ----
    const int i4 = ((bid - 1376) * 256 + t) * 4;
    float4 v4 = *(const float4*)(x + i4);
    _Float16 o[4] = {(_Float16)v4.x, (_Float16)v4.y, (_Float16)v4.z, (_Float16)v4.w};
    *(uint2*)(xh + i4) = *(const uint2*)o;
    return;
  }
  {  // ---- edge gather via LDS: one b per block ----
    const int b = bid - 1504;
    __shared__ float ed[E_ * 4];  // 63KB
    for (int i = t; i < E_; i += 256) {
      *(float4*)&ed[i * 4] = *(const float4*)(edges + ((size_t)b * E_ + i) * 4);
    }
    __syncthreads();
    for (int v = 0; v < V_; ++v) {
      if (t < 192) {
        const int tt = t >> 6, r = t & 63;
        float val = 0.f;
        if (r < 63) {
          const int u = (r < v) ? r : r + 1;
          const int vv = (v > u) ? v - 1 : v;
          val = ed[(u * 63 + vv) * 4 + tt + 1];
        }
        ewT[((size_t)(b * V_ + v)) * 192 + t] = val;
      }
    }
    return;
  }
}

// ---------------- Kernel 2: per (b,v) edge MFMA, 2x2 wave split ----------------
// Wave (mh,nhh): rows mh*32..+31, cols nhh*64..+63. af built once per row-half
// (2x less VALU + 2x fewer LDS gathers than col-split). h1s slice staged in
// LDS with XOR swizzle. b2 folded into C-init. XCD swizzle for L2 residency.
__global__ void __launch_bounds__(256)
edge_mfma(const float* __restrict__ b2, const _Float16* __restrict__ h1r,
          const _Float16* __restrict__ h1s, const _Float16* __restrict__ w2f,
          const float* __restrict__ ewT, _Float16* __restrict__ aggh) {
  const int bid = blockIdx.x;
  const int nb = (bid & 7) * 512 + (bid >> 3);  // bijective: 4096 % 8 == 0
  const int b = nb >> 6, v = nb & 63;
  const int t = threadIdx.x;
  const int wave = t >> 6, lane = t & 63;
  const int mh = wave & 1, nhh = wave >> 1;
  const int l15 = lane & 15, lg = lane >> 4;

  __shared__ __align__(16) _Float16 hsl[64 * HID_];  // 16KB, swizzled rows
  __shared__ float pshare[2][HID_];                  // cross-wave agg partials

  float acc[2][4][4];
#pragma unroll
  for (int m = 0; m < 2; ++m)
#pragma unroll
    for (int nt = 0; nt < 4; ++nt)
#pragma unroll
      for (int r = 0; r < 4; ++r) acc[m][nt][r] = 0.f;

  int urow[2];
#pragma unroll
  for (int m = 0; m < 2; ++m) {
    const int r = mh * 32 + m * 16 + l15;
    int u = (r < v) ? r : r + 1;
    if (r == 63) u = v;  // dummy row, ew=0
    urow[m] = u;
  }

  float b2r[4];
#pragma unroll
  for (int tt = 0; tt < 3; ++tt) {
    // ---- stage h1s[tt][b][*] -> LDS (coalesced, swizzled) ----
    const char* hsb = (const char*)(h1s + ((size_t)(tt * B_ + b) * V_) * HID_);
#pragma unroll
    for (int q = 0; q < 4; ++q) {
      const int byteoff = q * 4096 + t * 16;
      const int row = (byteoff >> 8) & 7;
      f16x8 val = *(const f16x8*)(hsb + byteoff);
      *(f16x8*)((char*)hsl + (byteoff ^ (row << 4))) = val;
    }

    const _Float16* hrp = h1r + ((size_t)(tt * B_ + b) * V_ + v) * HID_;
    f16x8 hr[4];
#pragma unroll
    for (int ks = 0; ks < 4; ++ks) hr[ks] = *(const f16x8*)(hrp + ks * 32 + lg * 8);

    f16x8 bf[4][4];
#pragma unroll
    for (int nt = 0; nt < 4; ++nt) {
#pragma unroll
      for (int ks = 0; ks < 4; ++ks)
        bf[nt][ks] = *(const f16x8*)(
            w2f + (size_t)(((((tt * 2 + nhh) * 4 + nt) * 4 + ks) * 64 + lane)) * 8);
      b2r[nt] = b2[(tt + 1) * HID_ + nhh * 64 + nt * 16 + l15];
    }
    __syncthreads();

#pragma unroll
    for (int m = 0; m < 2; ++m) {
      const int u = urow[m];
      const char* ubase = (const char*)hsl + u * 256;
      const int sw = (u & 7) << 4;
      f16x8 af[4];
#pragma unroll
      for (int ks = 0; ks < 4; ++ks) {
        f16x8 hs = *(const f16x8*)(ubase + ((ks * 64 + lg * 16) ^ sw));
        af[ks] = __builtin_elementwise_max(hr[ks] + hs, (f16x8)0);
      }
      const float4 ew4 = *(const float4*)(ewT + (size_t)nb * 192 + tt * 64 +
                                          (mh * 2 + m) * 16 + lg * 4);
#pragma unroll
      for (int nt = 0; nt < 4; ++nt) {
        f32x4 macc = {b2r[nt], b2r[nt], b2r[nt], b2r[nt]};
#pragma unroll
        for (int ks = 0; ks < 4; ++ks)
          macc = __builtin_amdgcn_mfma_f32_16x16x32_f16(af[ks], bf[nt][ks], macc, 0, 0, 0);
        acc[m][nt][0] += fmaxf(macc[0], 0.f) * ew4.x;
        acc[m][nt][1] += fmaxf(macc[1], 0.f) * ew4.y;
        acc[m][nt][2] += fmaxf(macc[2], 0.f) * ew4.z;
        acc[m][nt][3] += fmaxf(macc[3], 0.f) * ew4.w;
      }
    }
    __syncthreads();  // before restage
  }

  // ---- reduce: within-wave over 32 rows, then cross-wave (mh) via LDS ----
#pragma unroll
  for (int nt = 0; nt < 4; ++nt) {
    float s = 0.f;
#pragma unroll
    for (int m = 0; m < 2; ++m)
#pragma unroll
      for (int r = 0; r < 4; ++r) s += acc[m][nt][r];
    s += __shfl_xor(s, 16);
    s += __shfl_xor(s, 32);
    if (lane < 16) pshare[mh][nhh * 64 + nt * 16 + l15] = s;
  }
  __syncthreads();
  if (t < HID_)
    aggh[(size_t)nb * HID_ + t] = (_Float16)(pshare[0][t] + pshare[1][t]);
}

// ---------------- Kernel 3: output MLP via MFMA, 16 nodes/block (256 blocks) ----------------
__global__ void __launch_bounds__(256)
out_mlp(const float* __restrict__ x, const _Float16* __restrict__ xh,
        const _Float16* __restrict__ aggh, const _Float16* __restrict__ fc1f,
        const float* __restrict__ fc1b, const _Float16* __restrict__ fc2f,
        const float* __restrict__ fc2b, const _Float16* __restrict__ muf,
        const float* __restrict__ mub, float* __restrict__ out) {
  const int t = threadIdx.x;
  const int lane = t & 63, l15 = lane & 15, lg = lane >> 4;
  const int w = t >> 6;
  const int nb = blockIdx.x * 16;

  __shared__ __align__(16) _Float16 p1h[16][136];
  __shared__ __align__(16) _Float16 p2h[16][136];

  const int arow = nb + l15;

  float4 acc1[2];
#pragma unroll
  for (int nt = 0; nt < 2; ++nt) {
    const float bias = fc1b[w * 32 + nt * 16 + l15];
    acc1[nt] = {bias, bias, bias, bias};
  }
#pragma unroll
  for (int ks = 0; ks < 5; ++ks) {
    f16x8 af = (ks == 0)
                   ? *(const f16x8*)(xh + (size_t)arow * IN_ + lg * 8)
                   : *(const f16x8*)(aggh + (size_t)arow * HID_ + (ks - 1) * 32 + lg * 8);
#pragma unroll
    for (int nt = 0; nt < 2; ++nt) {
      f16x8 bf = *(const f16x8*)(fc1f + (size_t)((((w * 2 + nt) * 5 + ks) * 64 + lane)) * 8);
      *(f32x4*)&acc1[nt] =
          __builtin_amdgcn_mfma_f32_16x16x32_f16(af, bf, *(f32x4*)&acc1[nt], 0, 0, 0);
    }
  }
#pragma unroll
  for (int nt = 0; nt < 2; ++nt) {
    const int col = w * 32 + nt * 16 + l15;
#pragma unroll
    for (int r = 0; r < 4; ++r)
      p1h[lg * 4 + r][col] = (_Float16)fmaxf(((const float*)&acc1[nt])[r], 0.f);
  }
  __syncthreads();

  float4 acc2[2];
#pragma unroll
  for (int nt = 0; nt < 2; ++nt) {
    const float bias = fc2b[w * 32 + nt * 16 + l15];
    acc2[nt] = {bias, bias, bias, bias};
  }
#pragma unroll
  for (int ks = 0; ks < 4; ++ks) {
    f16x8 af = *(const f16x8*)&p1h[l15][ks * 32 + lg * 8];
#pragma unroll
    for (int nt = 0; nt < 2; ++nt) {
      f16x8 bf = *(const f16x8*)(fc2f + (size_t)((((w * 2 + nt) * 4 + ks) * 64 + lane)) * 8);
      *(f32x4*)&acc2[nt] =
          __builtin_amdgcn_mfma_f32_16x16x32_f16(af, bf, *(f32x4*)&acc2[nt], 0, 0, 0);
    }
  }
#pragma unroll
  for (int nt = 0; nt < 2; ++nt) {
    const int col = w * 32 + nt * 16 + l15;
#pragma unroll
    for (int r = 0; r < 4; ++r)
      p2h[lg * 4 + r][col] = (_Float16)fmaxf(((const float*)&acc2[nt])[r], 0.f);
  }
  __syncthreads();

  if (w < 2) {
    const int col = w * 16 + l15;
    const float mb = mub[col];
    float4 acc3 = {mb, mb, mb, mb};
#pragma unroll
    for (int ks = 0; ks < 4; ++ks) {
      f16x8 af = *(const f16x8*)&p2h[l15][ks * 32 + lg * 8];
      f16x8 bf = *(const f16x8*)(muf + (size_t)(((w * 4 + ks) * 64 + lane)) * 8);
      *(f32x4*)&acc3 = __builtin_amdgcn_mfma_f32_16x16x32_f16(af, bf, *(f32x4*)&acc3, 0, 0, 0);
    }
#pragma unroll
    for (int r = 0; r < 4; ++r) {
      const int node = nb + lg * 4 + r;
      out[(size_t)node * IN_ + col] = x[(size_t)node * IN_ + col] + ((const float*)&acc3)[r];
    }
  }
}

extern "C" void kernel_launch(void* const* d_in, const int* in_sizes, int n_in,
                              void* d_out, int out_size, void* d_ws, size_t ws_size,
                              hipStream_t stream) {
  const float* x     = (const float*)d_in[0];
  const float* edges = (const float*)d_in[1];
  const float* w1    = (const float*)d_in[2];
  const float* b1    = (const float*)d_in[3];
  const float* w2    = (const float*)d_in[4];
  const float* b2    = (const float*)d_in[5];
  const float* fc1w  = (const float*)d_in[6];
  const float* fc1b  = (const float*)d_in[7];
  const float* fc2w  = (const float*)d_in[8];
  const float* fc2b  = (const float*)d_in[9];
  const float* muw   = (const float*)d_in[10];
  const float* mub   = (const float*)d_in[11];
  float* out = (float*)d_out;

  float* ewT    = (float*)d_ws;                         // 4096*192 f32
  _Float16* h1r = (_Float16*)(ewT + (size_t)BV_ * 192); // 3*4096*128
  _Float16* h1s = h1r + (size_t)3 * BV_ * HID_;         // 3*4096*128
  _Float16* w2f = h1s + (size_t)3 * BV_ * HID_;         // 49152
  _Float16* fc1f = w2f + 49152;                         // 20480
  _Float16* fc2f = fc1f + 20480;                        // 16384
  _Float16* muf  = fc2f + 16384;                        // 4096
  _Float16* xh   = muf + 4096;                          // 4096*32
  _Float16* aggh = xh + (size_t)BV_ * IN_;              // 4096*128

  prep_all<<<1568, 256, 0, stream>>>(x, w1, b1, w2, edges, fc1w, fc2w, muw,
                                     h1r, h1s, w2f, fc1f, fc2f, muf, xh, ewT);
  edge_mfma<<<BV_, 256, 0, stream>>>(b2, h1r, h1s, w2f, ewT, aggh);
  out_mlp<<<BV_ / 16, 256, 0, stream>>>(x, xh, aggh, fc1f, fc1b, fc2f, fc2b,
                                        muf, mub, out);
}